// Round 1
// baseline (309.940 us; speedup 1.0000x reference)
//
#include <hip/hip_runtime.h>
#include <math.h>

#define BB 128
#define NN 256
#define EE 2048
#define BINS 16
#define HTS 36   // hT row stride (floats): float4-aligned, banks (4*row+c)%32

// ---------------- CSR build, both sides: g in [0,2B) ----------------
__global__ void csr_kernel(const int* __restrict__ eq, const int* __restrict__ ec,
                           int* __restrict__ off, int* __restrict__ srcs,
                           float* __restrict__ wts) {
    int g = blockIdx.x;                 // 0..2B-1
    int b = g < BB ? g : g - BB;
    const int* ei = g < BB ? eq : ec;
    int t = threadIdx.x;  // 256
    __shared__ int cnt[NN];
    __shared__ int sa[NN], sb[NN];
    __shared__ int cursor[NN];
    __shared__ float dvs[NN];
    cnt[t] = 0;
    __syncthreads();
    const int* src = ei + b * 2 * EE;
    const int* dst = src + EE;
    for (int e = t; e < EE; e += 256) atomicAdd(&cnt[dst[e]], 1);
    __syncthreads();
    dvs[t] = rsqrtf((float)cnt[t] + 1.0f);
    sa[t] = cnt[t];
    __syncthreads();
    int* pin = sa; int* pout = sb;
    for (int d = 1; d < NN; d <<= 1) {
        int v = pin[t];
        if (t >= d) v += pin[t - d];
        pout[t] = v;
        __syncthreads();
        int* tmp = pin; pin = pout; pout = tmp;
    }
    int excl = pin[t] - cnt[t];
    off[g * 257 + t] = excl;
    if (t == 255) off[g * 257 + 256] = EE;
    cursor[t] = excl;
    __syncthreads();
    for (int e = t; e < EE; e += 256) {
        int d = dst[e], s = src[e];
        int pos = atomicAdd(&cursor[d], 1);
        srcs[g * EE + pos] = s;
        wts[g * EE + pos] = dvs[s] * dvs[d];
    }
}

// ---------------- fused GCN layer: 256 thr, per-thread 4 rows x 8 cols ----------------
// chunk = 256 nodes x 32 cols. LDS ~73KB -> 2 blocks/CU. grid: (FOUT/32) * 2B.
template<int FIN, int FOUT, bool RELU>
__global__ __launch_bounds__(256, 2) void gcn_fused2(
        const float* __restrict__ X0, const float* __restrict__ X1,
        const float* __restrict__ W, const float* __restrict__ bias,
        const int* __restrict__ off, const int* __restrict__ srcs,
        const float* __restrict__ wts, float* __restrict__ OUT) {
    int blk = blockIdx.x;
    int g = blk % (2 * BB);
    int cb = (blk / (2 * BB)) * 32;
    int t = threadIdx.x;

    __shared__ float hT[NN * HTS];     // 36.9 KB
    __shared__ float xsT[16 * 260];    // 16.6 KB, k-major [k][n]
    __shared__ float wt[16 * 32];      // 2 KB   [k][c]
    __shared__ int   eoff[NN + 1];
    __shared__ int   esrc[EE];
    __shared__ float ewt[EE];

    const float* xg = (g < BB) ? (X0 + (size_t)g * NN * FIN)
                               : (X1 + (size_t)(g - BB) * NN * FIN);
    const int* o = off + g * 257;
    const int* sr = srcs + (size_t)g * EE;
    const float* wg = wts + (size_t)g * EE;

    // stage edges + offsets (coalesced; overlaps k-loop prologue)
    for (int i = t; i < EE; i += 256) { esrc[i] = sr[i]; ewt[i] = wg[i]; }
    for (int i = t; i <= NN; i += 256) eoff[i] = o[i];

    int l = t & 63;        // row quad: rows 4l..4l+3 (every wave covers all 256 rows)
    int wv = t >> 6;       // wave -> col octet: cols 8wv..8wv+7

    float acc[4][8];
#pragma unroll
    for (int i = 0; i < 4; i++)
#pragma unroll
        for (int j = 0; j < 8; j++) acc[i][j] = 0.f;

    // prefetch: thread t stages the 16-float k-window of row t
    const float* xr = xg + t * FIN;
    float xa[16];
    *(float4*)&xa[0]  = *(const float4*)(xr);
    *(float4*)&xa[4]  = *(const float4*)(xr + 4);
    *(float4*)&xa[8]  = *(const float4*)(xr + 8);
    *(float4*)&xa[12] = *(const float4*)(xr + 12);
    int wrow = t >> 4, wcol = (t & 15) * 2;
    float2 wreg = *(const float2*)&W[wrow * FOUT + cb + wcol];

    for (int k0 = 0; k0 < FIN; k0 += 16) {
#pragma unroll
        for (int m = 0; m < 16; m++) xsT[m * 260 + t] = xa[m];  // 2-way bank = free
        *(float2*)&wt[wrow * 32 + wcol] = wreg;
        __syncthreads();
        if (k0 + 16 < FIN) {
            xr += 16;
            *(float4*)&xa[0]  = *(const float4*)(xr);
            *(float4*)&xa[4]  = *(const float4*)(xr + 4);
            *(float4*)&xa[8]  = *(const float4*)(xr + 8);
            *(float4*)&xa[12] = *(const float4*)(xr + 12);
            wreg = *(const float2*)&W[(k0 + 16 + wrow) * FOUT + cb + wcol];
        }
#pragma unroll
        for (int k = 0; k < 16; k++) {
            float4 xv = *(const float4*)&xsT[k * 260 + 4 * l];          // lane-varying b128
            float4 wa = *(const float4*)&wt[k * 32 + 8 * wv];           // wave-uniform broadcast
            float4 wb = *(const float4*)&wt[k * 32 + 8 * wv + 4];
            float xq4[4] = {xv.x, xv.y, xv.z, xv.w};
            float wc8[8] = {wa.x, wa.y, wa.z, wa.w, wb.x, wb.y, wb.z, wb.w};
#pragma unroll
            for (int i = 0; i < 4; i++)
#pragma unroll
                for (int j = 0; j < 8; j++) acc[i][j] += xq4[i] * wc8[j];
        }
        __syncthreads();
    }
#pragma unroll
    for (int i = 0; i < 4; i++) {
        *(float4*)&hT[(4 * l + i) * HTS + 8 * wv] =
            make_float4(acc[i][0], acc[i][1], acc[i][2], acc[i][3]);
        *(float4*)&hT[(4 * l + i) * HTS + 8 * wv + 4] =
            make_float4(acc[i][4], acc[i][5], acc[i][6], acc[i][7]);
    }
    __syncthreads();

    // CSR-gather aggregation, 1-deep pipelined (esrc -> hT dependent LDS chain)
    int c = t & 31, ng = t >> 5;
    float bb_ = bias[cb + c];
    float* outp = OUT + (size_t)g * NN * FOUT;
    for (int n = ng; n < NN; n += 8) {
        int j0 = eoff[n], j1 = eoff[n + 1];
        float a = 0.f;
        int j = j0;
        if (j < j1) {
            int s0 = esrc[j];
            float w0 = ewt[j];
            for (++j; j < j1; ++j) {
                int s1 = esrc[j];
                float w1 = ewt[j];
                a += hT[s0 * HTS + c] * w0;
                s0 = s1; w0 = w1;
            }
            a += hT[s0 * HTS + c] * w0;
        }
        float d0i = 1.0f / ((float)(j1 - j0) + 1.0f);   // self-loop norm 1/deg
        float val = a + hT[n * HTS + c] * d0i + bb_;
        if (RELU) val = fmaxf(val, 0.f);
        outp[n * FOUT + cb + c] = val;
    }
}

// ---------------- attention pooling (both sides): one block per graph ----------------
__global__ void attpool_kernel(const float* __restrict__ X, const float* __restrict__ Watt,
                               float* __restrict__ e) {
    int g = blockIdx.x;   // 0..2B-1
    int t = threadIdx.x;
    __shared__ float xs[NN * 33];
    __shared__ float red[256];
    __shared__ float mean_s[32], ctx_s[32], sc[NN];
    const float* x = X + (size_t)g * NN * 32;
    for (int i = t; i < NN * 32; i += 256) { int n = i >> 5, c = i & 31; xs[n * 33 + c] = x[i]; }
    __syncthreads();
    {
        int c = t & 31, p = t >> 5;
        float s = 0.f;
        for (int n = p * 32; n < (p + 1) * 32; n++) s += xs[n * 33 + c];
        red[t] = s;
    }
    __syncthreads();
    if (t < 32) {
        float m = 0.f;
        for (int p = 0; p < 8; p++) m += red[p * 32 + t];
        mean_s[t] = m / (float)NN;
    }
    __syncthreads();
    if (t < 32) {
        float a = 0.f;
        for (int f = 0; f < 32; f++) a += mean_s[f] * Watt[t * 32 + f];
        ctx_s[t] = tanhf(a);
    }
    __syncthreads();
    {
        float a = 0.f;
        for (int f = 0; f < 32; f++) a += xs[t * 33 + f] * ctx_s[f];
        sc[t] = 1.f / (1.f + expf(-a));
    }
    __syncthreads();
    {
        int c = t & 31, p = t >> 5;
        float s = 0.f;
        for (int n = p * 32; n < (p + 1) * 32; n++) s += xs[n * 33 + c] * sc[n];
        red[t] = s;
    }
    __syncthreads();
    if (t < 32) {
        float s = 0.f;
        for (int p = 0; p < 8; p++) s += red[p * 32 + t];
        e[g * 32 + t] = s;
    }
}

// ---------------- pairwise dots: 128x128 tile, 8x8 per thread, f-major LDS ----------------
// Per thread: rows {4rg+i, 64+4rg+i}, cols {4cg+j, 64+4cg+j}. q-reads broadcast,
// c-reads 64-consecutive-dword b128 (2-way bank = free). 32B LDS per 64 FMAs.
#define PD_STAGE_AND_DOT \
    int blk = blockIdx.x; \
    int b = blk >> 2; \
    int tq = (blk >> 1) & 1, tc = blk & 1; \
    __shared__ float qsT[32 * 132]; \
    __shared__ float csT[32 * 132]; \
    int t = threadIdx.x; \
    { \
        int n = t >> 1, f0 = (t & 1) * 16; \
        const float* qp = Q + ((size_t)b * NN + tq * 128 + n) * 32 + f0; \
        const float* cp = C + ((size_t)b * NN + tc * 128 + n) * 32 + f0; \
        float qa16[16], ca16[16]; \
        *(float4*)&qa16[0]  = *(const float4*)(qp); \
        *(float4*)&qa16[4]  = *(const float4*)(qp + 4); \
        *(float4*)&qa16[8]  = *(const float4*)(qp + 8); \
        *(float4*)&qa16[12] = *(const float4*)(qp + 12); \
        *(float4*)&ca16[0]  = *(const float4*)(cp); \
        *(float4*)&ca16[4]  = *(const float4*)(cp + 4); \
        *(float4*)&ca16[8]  = *(const float4*)(cp + 8); \
        *(float4*)&ca16[12] = *(const float4*)(cp + 12); \
        _Pragma("unroll") \
        for (int m = 0; m < 16; m++) { \
            qsT[(f0 + m) * 132 + n] = qa16[m]; \
            csT[(f0 + m) * 132 + n] = ca16[m]; \
        } \
    } \
    __syncthreads(); \
    int rg = (t >> 4) * 4, cg = (t & 15) * 4; \
    float acc[8][8]; \
    _Pragma("unroll") \
    for (int i = 0; i < 8; i++) \
        _Pragma("unroll") \
        for (int j = 0; j < 8; j++) acc[i][j] = 0.f; \
    _Pragma("unroll 2") \
    for (int f = 0; f < 32; f++) { \
        float4 qa = *(const float4*)&qsT[f * 132 + rg]; \
        float4 qb = *(const float4*)&qsT[f * 132 + 64 + rg]; \
        float4 ca = *(const float4*)&csT[f * 132 + cg]; \
        float4 cb = *(const float4*)&csT[f * 132 + 64 + cg]; \
        float qv[8] = {qa.x, qa.y, qa.z, qa.w, qb.x, qb.y, qb.z, qb.w}; \
        float cv[8] = {ca.x, ca.y, ca.z, ca.w, cb.x, cb.y, cb.z, cb.w}; \
        _Pragma("unroll") \
        for (int i = 0; i < 8; i++) \
            _Pragma("unroll") \
            for (int j = 0; j < 8; j++) acc[i][j] += qv[i] * cv[j]; \
    }

__global__ __launch_bounds__(256, 4) void pairdot_minmax(
        const float* __restrict__ Q, const float* __restrict__ C,
        float* __restrict__ bmin, float* __restrict__ bmax) {
    PD_STAGE_AND_DOT
    float lmin = acc[0][0], lmax = acc[0][0];
#pragma unroll
    for (int i = 0; i < 8; i++)
#pragma unroll
        for (int j = 0; j < 8; j++) {
            lmin = fminf(lmin, acc[i][j]);
            lmax = fmaxf(lmax, acc[i][j]);
        }
    __shared__ float rmin[256], rmax[256];
    rmin[t] = lmin; rmax[t] = lmax;
    __syncthreads();
    for (int s = 128; s > 0; s >>= 1) {
        if (t < s) { rmin[t] = fminf(rmin[t], rmin[t + s]); rmax[t] = fmaxf(rmax[t], rmax[t + s]); }
        __syncthreads();
    }
    if (t == 0) { bmin[blk] = rmin[0]; bmax[blk] = rmax[0]; }
}

// ---------------- global min/max reduce (1 block) + zero counts ----------------
__global__ void minmax_kernel(const float* __restrict__ bmin, const float* __restrict__ bmax,
                              float* __restrict__ lohi, float* __restrict__ counts) {
    __shared__ float rmin[256], rmax[256];
    int t = threadIdx.x;
    float lmin = 1e30f, lmax = -1e30f;
    for (int i = t; i < 512; i += 256) { lmin = fminf(lmin, bmin[i]); lmax = fmaxf(lmax, bmax[i]); }
    rmin[t] = lmin; rmax[t] = lmax;
    __syncthreads();
    for (int s = 128; s > 0; s >>= 1) {
        if (t < s) { rmin[t] = fminf(rmin[t], rmin[t + s]); rmax[t] = fmaxf(rmax[t], rmax[t + s]); }
        __syncthreads();
    }
    if (t == 0) { lohi[0] = rmin[0]; lohi[1] = rmax[0]; }
    if (t < BINS) counts[t] = 0.f;
}

// ---------------- pass 2: recompute dots, bit-sliced ballot histogram ----------------
__global__ __launch_bounds__(256, 4) void pairdot_hist(
        const float* __restrict__ Q, const float* __restrict__ C,
        const float* __restrict__ lohi, float* __restrict__ counts) {
    PD_STAGE_AND_DOT
    float lo = lohi[0], hi = lohi[1];
    float scale = (float)BINS / (hi - lo);
    int lane = t & 63;
    int cnt = 0;   // lane L accumulates count for bin (L & 15)
#pragma unroll
    for (int i = 0; i < 8; i++)
#pragma unroll
        for (int j = 0; j < 8; j++) {
            int idx = (int)floorf((acc[i][j] - lo) * scale);
            idx = min(max(idx, 0), BINS - 1);
            unsigned long long b0 = __ballot((idx & 1) != 0);
            unsigned long long b1 = __ballot((idx & 2) != 0);
            unsigned long long b2 = __ballot((idx & 4) != 0);
            unsigned long long b3 = __ballot((idx & 8) != 0);
            unsigned long long msk = ((lane & 1) ? b0 : ~b0);
            msk &= ((lane & 2) ? b1 : ~b1);
            msk &= ((lane & 4) ? b2 : ~b2);
            msk &= ((lane & 8) ? b3 : ~b3);
            cnt += __popcll(msk);
        }
    __shared__ float wbins[4][BINS];
    int wave = t >> 6;
    if (lane < BINS) wbins[wave][lane] = (float)cnt;
    __syncthreads();
    if (t < BINS) {
        atomicAdd(&counts[t], wbins[0][t] + wbins[1][t] + wbins[2][t] + wbins[3][t]);
    }
}

// ---------------- NTN + histogram concat + fc1 + fc2 head ----------------
__global__ void final_kernel(const float* __restrict__ e1, const float* __restrict__ e2,
                             const float* __restrict__ ntnW, const float* __restrict__ ntnV,
                             const float* __restrict__ ntnb, const float* __restrict__ counts,
                             const float* __restrict__ fc1W, const float* __restrict__ fc1b,
                             const float* __restrict__ fc2W, const float* __restrict__ fc2b,
                             float* __restrict__ out) {
    int b = blockIdx.x;
    int t = threadIdx.x;
    __shared__ float a1[32], a2[32], red[256], z[32], u[16];
    if (t < 32) a1[t] = e1[b * 32 + t];
    else if (t < 64) a2[t - 32] = e2[b * 32 + t - 32];
    __syncthreads();
    int tt = t >> 4, g = t & 15;
    float p = 0.f;
#pragma unroll
    for (int ii = 0; ii < 2; ii++) {
        int i = g + 16 * ii;
        float d = 0.f;
        const float* wr = ntnW + (tt * 32 + i) * 32;
        for (int j = 0; j < 32; j++) d += wr[j] * a2[j];
        p += a1[i] * d;
    }
    red[t] = p;
    __syncthreads();
    if (t < 16) {
        float s = 0.f;
        for (int g2 = 0; g2 < 16; g2++) s += red[t * 16 + g2];
        float lin = ntnb[t];
        for (int i = 0; i < 32; i++) lin += ntnV[t * 64 + i] * a1[i];
        for (int i = 0; i < 32; i++) lin += ntnV[t * 64 + 32 + i] * a2[i];
        z[t] = fmaxf(s + lin, 0.f);
    } else if (t < 32) {
        float tot = 0.f;
        for (int i = 0; i < BINS; i++) tot += counts[i];
        z[t] = counts[t - 16] / tot;
    }
    __syncthreads();
    if (t < 16) {
        float a = fc1b[t];
        for (int i = 0; i < 32; i++) a += fc1W[t * 32 + i] * z[i];
        u[t] = fmaxf(a, 0.f);
    }
    __syncthreads();
    if (t == 0) {
        float a = fc2b[0];
        for (int i = 0; i < 16; i++) a += fc2W[i] * u[i];
        out[b] = 1.f / (1.f + expf(-a));
    }
}

extern "C" void kernel_launch(void* const* d_in, const int* in_sizes, int n_in,
                              void* d_out, int out_size, void* d_ws, size_t ws_size,
                              hipStream_t stream) {
    const float* xq   = (const float*)d_in[0];
    const float* xc   = (const float*)d_in[1];
    const int*   eq   = (const int*)d_in[2];
    const int*   ec   = (const int*)d_in[3];
    const float* W1   = (const float*)d_in[4];
    const float* b1   = (const float*)d_in[5];
    const float* W2   = (const float*)d_in[6];
    const float* b2   = (const float*)d_in[7];
    const float* W3   = (const float*)d_in[8];
    const float* b3   = (const float*)d_in[9];
    const float* Watt = (const float*)d_in[10];
    const float* ntnW = (const float*)d_in[11];
    const float* ntnV = (const float*)d_in[12];
    const float* ntnb = (const float*)d_in[13];
    const float* fc1W = (const float*)d_in[14];
    const float* fc1b = (const float*)d_in[15];
    const float* fc2W = (const float*)d_in[16];
    const float* fc2b = (const float*)d_in[17];
    float* out = (float*)d_out;
    float* ws  = (float*)d_ws;

    // ---- workspace layout (float indices), [2B] contiguous buffers ----
    float* O3   = ws;                           // 2*B*N*32  = 2097152
    float* e12  = O3 + 2097152;                 // 2*B*32    = 8192
    float* bmin = e12 + 8192;                   // 2048 (512 used)
    float* bmax = bmin + 2048;                  // 2048 (512 used)
    float* lohi = bmax + 2048;                  // 2
    float* cntw = lohi + 2;                     // 16
    int*   off  = (int*)(ws + 2109504);         // 2B*257 = 65792
    int*   srcs = off + 65792;                  // 2B*E = 524288
    float* wts  = (float*)(srcs + 524288);      // 524288
    float* O1   = ws + 3223872;                 // 2*B*N*128 = 8388608
    float* O2   = O1 + 8388608;                 // 2*B*N*64  = 4194304

    float* O3Q = O3;
    float* O3C = O3 + (size_t)BB * NN * 32;
    float* e1w = e12;
    float* e2w = e12 + BB * 32;

    csr_kernel<<<2 * BB, 256, 0, stream>>>(eq, ec, off, srcs, wts);

    gcn_fused2<128, 128, true><<<4 * 2 * BB, 256, 0, stream>>>(
        xq, xc, W1, b1, off, srcs, wts, O1);
    gcn_fused2<128, 64, true><<<2 * 2 * BB, 256, 0, stream>>>(
        O1, O1 + (size_t)BB * NN * 128, W2, b2, off, srcs, wts, O2);
    gcn_fused2<64, 32, false><<<1 * 2 * BB, 256, 0, stream>>>(
        O2, O2 + (size_t)BB * NN * 64, W3, b3, off, srcs, wts, O3);

    attpool_kernel<<<2 * BB, 256, 0, stream>>>(O3, Watt, e12);

    pairdot_minmax<<<BB * 4, 256, 0, stream>>>(O3Q, O3C, bmin, bmax);
    minmax_kernel<<<1, 256, 0, stream>>>(bmin, bmax, lohi, cntw);
    pairdot_hist<<<BB * 4, 256, 0, stream>>>(O3Q, O3C, lohi, cntw);

    final_kernel<<<BB, 256, 0, stream>>>(e1w, e2w, ntnW, ntnV, ntnb, cntw,
                                         fc1W, fc1b, fc2W, fc2b, out);
}